// Round 4
// baseline (1262.738 us; speedup 1.0000x reference)
//
#include <hip/hip_runtime.h>

#define N_USERS_C 100000
#define N_NODES_C 150000
#define D 64
#define NB 2344              // ceil(150000/64) row-buckets of 64 rows
#define CPAD 16              // cursor padding: 1 int per 64B line
#define SPAD 68              // transform transposed-tile row stride

// ---------------- Bucket histogram (LDS-privatized) ----------------
__global__ __launch_bounds__(256) void histb_k(
    const int* __restrict__ rows, int* __restrict__ bcountP, int nnz)
{
    __shared__ int lh[NB];
    for (int i = threadIdx.x; i < NB; i += 256) lh[i] = 0;
    __syncthreads();
    int gtid = blockIdx.x * blockDim.x + threadIdx.x;
    int stride = gridDim.x * blockDim.x;
    for (int e = gtid; e < nnz; e += stride)
        atomicAdd(&lh[rows[e] >> 6], 1);
    __syncthreads();
    for (int b = threadIdx.x; b < NB; b += 256) {
        int c = lh[b];
        if (c) atomicAdd(&bcountP[b * CPAD], c);
    }
}

// ---------------- Single-block exclusive scan over padded counts ----------------
__global__ __launch_bounds__(1024) void scanb_k(
    const int* __restrict__ bcountP, int* __restrict__ bstart, int n)
{
    __shared__ int wsum[16];
    __shared__ int woff[16];
    __shared__ int carry;
    __shared__ int tile_total;
    int lane = threadIdx.x & 63;
    int wid  = threadIdx.x >> 6;
    if (threadIdx.x == 0) carry = 0;
    __syncthreads();
    for (int base = 0; base < n; base += 1024) {
        int i = base + (int)threadIdx.x;
        int v = (i < n) ? bcountP[i * CPAD] : 0;
        int incl = v;
        #pragma unroll
        for (int off = 1; off < 64; off <<= 1) {
            int t = __shfl_up(incl, off);
            if (lane >= off) incl += t;
        }
        if (lane == 63) wsum[wid] = incl;
        __syncthreads();
        if (threadIdx.x == 0) {
            int run = 0;
            #pragma unroll
            for (int w = 0; w < 16; ++w) { int t = wsum[w]; woff[w] = run; run += t; }
            tile_total = run;
        }
        __syncthreads();
        if (i < n) bstart[i] = carry + woff[wid] + incl - v;
        __syncthreads();
        if (threadIdx.x == 0) carry += tile_total;
    }
    __syncthreads();
    if (threadIdx.x == 0) bstart[n] = carry;
}

__global__ __launch_bounds__(256) void initcur_k(
    const int* __restrict__ bstart, int* __restrict__ bcur, int n)
{
    int i = blockIdx.x * blockDim.x + threadIdx.x;
    if (i < n) bcur[i * CPAD] = bstart[i];
}

// ---------------- Bucketed edge scatter ----------------
// pairs[p] = ((rowlow6 << 18) | col, val_bits), bucket-grouped.
__global__ __launch_bounds__(256) void fillb_k(
    const int* __restrict__ rows, const int* __restrict__ cols,
    const float* __restrict__ vals, int* __restrict__ bcur,
    int2* __restrict__ pairs, int nnz)
{
    int gtid = blockIdx.x * blockDim.x + threadIdx.x;
    int stride = gridDim.x * blockDim.x;
    for (int e = gtid; e < nnz; e += stride) {
        int r = rows[e];
        int p = atomicAdd(&bcur[(r >> 6) * CPAD], 1);
        pairs[p] = make_int2(((r & 63) << 18) | cols[e], __float_as_int(vals[e]));
    }
}

// ---------------- Bucket gather: one block per 64-row bucket ----------------
// LDS 64x64 fp32 accumulator (lane = dim); edges streamed unsorted,
// (col,val) broadcast via readlane, ego row loaded coalesced, ds_add_f32.
__global__ __launch_bounds__(256) void bgather_k(
    const int* __restrict__ bstart, const int2* __restrict__ pairs,
    const float* __restrict__ ego, float* __restrict__ side)
{
    __shared__ float acc[64 * D];   // 16 KB
    int t = threadIdx.x, lane = t & 63, wid = t >> 6;
    for (int i = t * 4; i < 64 * D; i += 1024)
        *(float4*)&acc[i] = make_float4(0.f, 0.f, 0.f, 0.f);
    __syncthreads();

    int b = blockIdx.x;
    int s = bstart[b], e = bstart[b + 1];
    for (int base = s + wid * 64; base < e; base += 256) {
        int2 p = make_int2(0, 0);
        if (base + lane < e) p = pairs[base + lane];
        int cnt8 = (min(e - base, 64) + 7) & ~7;
        for (int j = 0; j < cnt8; j += 8) {
            int   pk[8]; float pv[8], f[8];
            #pragma unroll
            for (int k = 0; k < 8; ++k) {
                pk[k] = __builtin_amdgcn_readlane(p.x, j + k);
                pv[k] = __int_as_float(__builtin_amdgcn_readlane(p.y, j + k));
            }
            #pragma unroll
            for (int k = 0; k < 8; ++k)
                f[k] = ego[(size_t)(pk[k] & 0x3FFFF) * D + lane];
            #pragma unroll
            for (int k = 0; k < 8; ++k)
                atomicAdd(&acc[(pk[k] >> 18) * D + lane], pv[k] * f[k]);
        }
    }
    __syncthreads();

    int rbase = b * 64;
    for (int rr = wid; rr < 64; rr += 4) {
        int row = rbase + rr;
        if (row < N_NODES_C)
            side[(size_t)row * D + lane] = acc[rr * D + lane];
    }
}

// ---------------- Sampled gather (layer 2): one wave per sampled row ----------------
// Streams the row's bucket, ballot-matches rowlow, accumulates val*ego[col].
// Also copies ego[n] into egoc[r] for the bi-term.
__global__ __launch_bounds__(256) void sgather_k(
    const int* __restrict__ bstart, const int2* __restrict__ pairs,
    const float* __restrict__ ego, float* __restrict__ side,
    float* __restrict__ egoc,
    const int* __restrict__ u, const int* __restrict__ it,
    int nrows, int batch)
{
    int gtid = blockIdx.x * blockDim.x + threadIdx.x;
    int wave = gtid >> 6;
    int lane = threadIdx.x & 63;
    if (wave >= nrows) return;
    int r = wave;
    int n = (r < batch) ? u[r] : N_USERS_C + it[r - batch];
    int b = n >> 6, rl = n & 63;
    int s = bstart[b], e = bstart[b + 1];

    float acc = 0.0f;
    for (int base = s; base < e; base += 64) {
        int2 p = make_int2(-1, 0);
        if (base + lane < e) p = pairs[base + lane];
        unsigned long long mask = __ballot((p.x >> 18) == rl);
        while (mask) {
            int j = __builtin_ctzll(mask);
            mask &= mask - 1;
            int   c = __builtin_amdgcn_readlane(p.x, j) & 0x3FFFF;
            float v = __int_as_float(__builtin_amdgcn_readlane(p.y, j));
            acc = fmaf(v, ego[(size_t)c * D + lane], acc);
        }
    }
    side[(size_t)r * D + lane] = acc;
    egoc[(size_t)r * D + lane] = ego[(size_t)n * D + lane];
}

// ---------------- Tiled transform (unchanged from round 3) ----------------
__global__ __launch_bounds__(256) void transform_k(
    const float* __restrict__ S, const float* __restrict__ E,
    const float* __restrict__ Wg, const float* __restrict__ bg,
    const float* __restrict__ Wb, const float* __restrict__ bb,
    float* __restrict__ out, int nrows)
{
    __shared__ __align__(16) float sWg[D * D];
    __shared__ __align__(16) float sWb[D * D];
    __shared__ __align__(16) float sAT[D][SPAD];
    __shared__ __align__(16) float sBT[D][SPAD];

    int t  = threadIdx.x;
    int tc = t & 15;
    int tr = t >> 4;
    int r0 = blockIdx.x * 64;

    for (int i = t; i < D * D; i += 256) {
        sWg[i] = Wg[i];
        sWb[i] = Wb[i];
    }
    for (int itr = 0; itr < 4; ++itr) {
        int rr  = itr * 16 + (t >> 4);
        int row = r0 + rr;
        float4 sv = make_float4(0.f, 0.f, 0.f, 0.f);
        float4 ev = sv;
        if (row < nrows) {
            sv = *(const float4*)&S[(size_t)row * D + tc * 4];
            ev = *(const float4*)&E[(size_t)row * D + tc * 4];
        }
        sAT[tc * 4 + 0][rr] = sv.x;
        sAT[tc * 4 + 1][rr] = sv.y;
        sAT[tc * 4 + 2][rr] = sv.z;
        sAT[tc * 4 + 3][rr] = sv.w;
        sBT[tc * 4 + 0][rr] = sv.x * ev.x;
        sBT[tc * 4 + 1][rr] = sv.y * ev.y;
        sBT[tc * 4 + 2][rr] = sv.z * ev.z;
        sBT[tc * 4 + 3][rr] = sv.w * ev.w;
    }
    __syncthreads();

    float acc[4][4] = {};
    for (int k = 0; k < D; ++k) {
        float4 a4 = *(const float4*)&sAT[k][tr * 4];
        float4 b4 = *(const float4*)&sBT[k][tr * 4];
        float4 g4 = *(const float4*)&sWg[k * D + tc * 4];
        float4 w4 = *(const float4*)&sWb[k * D + tc * 4];
        float av[4] = {a4.x, a4.y, a4.z, a4.w};
        float bv[4] = {b4.x, b4.y, b4.z, b4.w};
        float gv[4] = {g4.x, g4.y, g4.z, g4.w};
        float wv[4] = {w4.x, w4.y, w4.z, w4.w};
        #pragma unroll
        for (int i = 0; i < 4; ++i)
            #pragma unroll
            for (int j = 0; j < 4; ++j)
                acc[i][j] = fmaf(av[i], gv[j], fmaf(bv[i], wv[j], acc[i][j]));
    }

    float4 bgv = *(const float4*)&bg[tc * 4];
    float4 bbv = *(const float4*)&bb[tc * 4];
    float bias[4] = {bgv.x + bbv.x, bgv.y + bbv.y, bgv.z + bbv.z, bgv.w + bbv.w};

    float vv[4][4];
    float ss[4] = {0.f, 0.f, 0.f, 0.f};
    #pragma unroll
    for (int i = 0; i < 4; ++i) {
        #pragma unroll
        for (int j = 0; j < 4; ++j) {
            float v = acc[i][j] + bias[j];
            v = (v > 0.0f) ? v : 0.2f * v;
            vv[i][j] = v;
            ss[i] += v * v;
        }
    }
    #pragma unroll
    for (int i = 0; i < 4; ++i) {
        #pragma unroll
        for (int off = 1; off < 16; off <<= 1)
            ss[i] += __shfl_xor(ss[i], off);
    }
    #pragma unroll
    for (int i = 0; i < 4; ++i) {
        int row = r0 + tr * 4 + i;
        if (row < nrows) {
            float inv = 1.0f / fmaxf(sqrtf(ss[i]), 1e-12f);
            float4 o = make_float4(vv[i][0] * inv, vv[i][1] * inv,
                                   vv[i][2] * inv, vv[i][3] * inv);
            *(float4*)&out[(size_t)row * D + tc * 4] = o;
        }
    }
}

// ---------------- Readout ----------------
__global__ __launch_bounds__(256) void gamma_k(
    const float* __restrict__ x, const float* __restrict__ e1,
    const float* __restrict__ e2c, const int* __restrict__ users,
    const int* __restrict__ items, float* __restrict__ gamma, int batch)
{
    int gtid = blockIdx.x * blockDim.x + threadIdx.x;
    int wave = gtid >> 6;
    int lane = threadIdx.x & 63;
    if (wave >= batch) return;
    size_t uu = (size_t)users[wave];
    size_t tt = (size_t)(N_USERS_C + items[wave]);
    float acc = x[uu * D + lane] * x[tt * D + lane]
              + e1[uu * D + lane] * e1[tt * D + lane]
              + e2c[(size_t)wave * D + lane] * e2c[(size_t)(batch + wave) * D + lane];
    #pragma unroll
    for (int off = 1; off < 64; off <<= 1) acc += __shfl_xor(acc, off);
    if (lane == 0) gamma[wave] = acc;
}

extern "C" void kernel_launch(void* const* d_in, const int* in_sizes, int n_in,
                              void* d_out, int out_size, void* d_ws, size_t ws_size,
                              hipStream_t stream) {
    const int*   rows  = (const int*)d_in[0];
    const int*   cols  = (const int*)d_in[1];
    const float* vals  = (const float*)d_in[2];
    const float* x     = (const float*)d_in[3];
    const int*   users = (const int*)d_in[4];
    const int*   items = (const int*)d_in[5];
    const float* Wg0 = (const float*)d_in[6];
    const float* bg0 = (const float*)d_in[7];
    const float* Wb0 = (const float*)d_in[8];
    const float* bb0 = (const float*)d_in[9];
    const float* Wg1 = (const float*)d_in[10];
    const float* bg1 = (const float*)d_in[11];
    const float* Wb1 = (const float*)d_in[12];
    const float* bb1 = (const float*)d_in[13];

    int nnz   = in_sizes[0];
    int batch = in_sizes[4];
    float* out = (float*)d_out;

    size_t emb = (size_t)N_NODES_C * D;
    float* A       = (float*)d_ws;                 // e1 [150k x 64]
    float* Sbuf    = A + emb;                      // side; reused for layer-2 compacts
    int*   bstart  = (int*)(Sbuf + emb);           // NB+1 (+1 pad for 8B alignment)
    int*   bcountP = bstart + (NB + 2);
    int*   bcur    = bcountP + NB * CPAD;
    int2*  pairs   = (int2*)(bcur + NB * CPAD);    // nnz  (offset is even -> 8B aligned)

    float* side2c = Sbuf;                          // [2B x 64]
    float* egoc   = Sbuf + (size_t)2 * 2048 * D;
    float* e2c    = egoc + (size_t)2 * 2048 * D;

    // --- bucket build ---
    hipMemsetAsync(bcountP, 0, NB * CPAD * sizeof(int), stream);
    histb_k<<<256, 256, 0, stream>>>(rows, bcountP, nnz);
    scanb_k<<<1, 1024, 0, stream>>>(bcountP, bstart, NB);
    initcur_k<<<(NB + 255) / 256, 256, 0, stream>>>(bstart, bcur, NB);
    fillb_k<<<2048, 256, 0, stream>>>(rows, cols, vals, bcur, pairs, nnz);

    // --- Layer 1 (all nodes) ---
    bgather_k<<<NB, 256, 0, stream>>>(bstart, pairs, x, Sbuf);
    transform_k<<<(N_NODES_C + 63) / 64, 256, 0, stream>>>(
        Sbuf, x, Wg0, bg0, Wb0, bb0, A, N_NODES_C);

    // --- Layer 2 (sampled 2*batch rows) ---
    sgather_k<<<(2 * batch * 64 + 255) / 256, 256, 0, stream>>>(
        bstart, pairs, A, side2c, egoc, users, items, 2 * batch, batch);
    transform_k<<<(2 * batch + 63) / 64, 256, 0, stream>>>(
        side2c, egoc, Wg1, bg1, Wb1, bb1, e2c, 2 * batch);

    // --- Readout ---
    gamma_k<<<(batch * 64 + 255) / 256, 256, 0, stream>>>(
        x, A, e2c, users, items, out, batch);
}

// Round 5
// 446.448 us; speedup vs baseline: 2.8284x; 2.8284x over previous
//
#include <hip/hip_runtime.h>

#define N_USERS_C 100000
#define N_NODES_C 150000
#define D 64
#define NB 2344              // ceil(150000/64) row-buckets of 64 rows
#define CPAD 16              // global bucket cursor padding: 1 int per 64B line
#define SPAD 68              // transform transposed-tile row stride
#define BCAP 2048            // per-bucket LDS sort capacity (mean 1024, sigma 32)

// ---------------- Bucket histogram (LDS-privatized) ----------------
__global__ __launch_bounds__(256) void histb_k(
    const int* __restrict__ rows, int* __restrict__ bcountP, int nnz)
{
    __shared__ int lh[NB];
    for (int i = threadIdx.x; i < NB; i += 256) lh[i] = 0;
    __syncthreads();
    int gtid = blockIdx.x * blockDim.x + threadIdx.x;
    int stride = gridDim.x * blockDim.x;
    for (int e = gtid; e < nnz; e += stride)
        atomicAdd(&lh[rows[e] >> 6], 1);
    __syncthreads();
    for (int b = threadIdx.x; b < NB; b += 256) {
        int c = lh[b];
        if (c) atomicAdd(&bcountP[b * CPAD], c);
    }
}

// ---------------- Single-block exclusive scan over padded counts ----------------
__global__ __launch_bounds__(1024) void scanb_k(
    const int* __restrict__ bcountP, int* __restrict__ bstart, int n)
{
    __shared__ int wsum[16];
    __shared__ int woff[16];
    __shared__ int carry;
    __shared__ int tile_total;
    int lane = threadIdx.x & 63;
    int wid  = threadIdx.x >> 6;
    if (threadIdx.x == 0) carry = 0;
    __syncthreads();
    for (int base = 0; base < n; base += 1024) {
        int i = base + (int)threadIdx.x;
        int v = (i < n) ? bcountP[i * CPAD] : 0;
        int incl = v;
        #pragma unroll
        for (int off = 1; off < 64; off <<= 1) {
            int t = __shfl_up(incl, off);
            if (lane >= off) incl += t;
        }
        if (lane == 63) wsum[wid] = incl;
        __syncthreads();
        if (threadIdx.x == 0) {
            int run = 0;
            #pragma unroll
            for (int w = 0; w < 16; ++w) { int t = wsum[w]; woff[w] = run; run += t; }
            tile_total = run;
        }
        __syncthreads();
        if (i < n) bstart[i] = carry + woff[wid] + incl - v;
        __syncthreads();
        if (threadIdx.x == 0) carry += tile_total;
    }
    __syncthreads();
    if (threadIdx.x == 0) bstart[n] = carry;
}

// bcur = bstart (padded); also rowptr[N] = nnz.
__global__ __launch_bounds__(256) void initcur_k(
    const int* __restrict__ bstart, int* __restrict__ bcur,
    int* __restrict__ rowptr, int n, int nnz)
{
    int i = blockIdx.x * blockDim.x + threadIdx.x;
    if (i < n) bcur[i * CPAD] = bstart[i];
    if (i == 0) rowptr[N_NODES_C] = nnz;
}

// ---------------- Privatized bucket fill ----------------
// Each block counts its contiguous edge chunk per bucket in LDS, reserves one
// global range per touched bucket (1 atomic), then scatters via LDS cursors.
// pairs[p] = ((rowlow6 << 18) | col, val_bits), bucket-grouped (unsorted inside).
__global__ __launch_bounds__(256) void fillb_k(
    const int* __restrict__ rows, const int* __restrict__ cols,
    const float* __restrict__ vals, int* __restrict__ bcurP,
    int2* __restrict__ pairs, int nnz)
{
    __shared__ int lcnt[NB];
    __shared__ int lbase[NB];
    int t = threadIdx.x;
    for (int i = t; i < NB; i += 256) lcnt[i] = 0;
    __syncthreads();
    int per = (nnz + gridDim.x - 1) / gridDim.x;
    int s = blockIdx.x * per;
    int e = min(nnz, s + per);
    for (int i = s + t; i < e; i += 256)
        atomicAdd(&lcnt[rows[i] >> 6], 1);
    __syncthreads();
    for (int i = t; i < NB; i += 256) {
        int c = lcnt[i];
        lbase[i] = c ? atomicAdd(&bcurP[i * CPAD], c) : 0;
        lcnt[i] = 0;                       // reuse as local cursor
    }
    __syncthreads();
    for (int i = s + t; i < e; i += 256) {
        int r = rows[i];
        int b = r >> 6;
        int slot = lbase[b] + atomicAdd(&lcnt[b], 1);
        pairs[slot] = make_int2(((r & 63) << 18) | cols[i], __float_as_int(vals[i]));
    }
}

// ---------------- Per-bucket LDS counting sort -> exact CSR ----------------
// One block per bucket: stage pairs in LDS, count 64 rows, wave-scan, scatter
// in LDS, write back contiguously (coalesced). Also emits rowptr for the
// bucket's 64 rows. Drops the rowlow tag (output is clean (col,val)).
__global__ __launch_bounds__(256) void sortb_k(
    const int* __restrict__ bstart, int2* __restrict__ pairs,
    int* __restrict__ rowptr)
{
    __shared__ int2 buf[BCAP];
    __shared__ int2 obuf[BCAP];
    __shared__ int cnt[64];
    __shared__ int cur[64];
    int b = blockIdx.x;
    int s = bstart[b], e = bstart[b + 1];
    int m = e - s;                          // <= BCAP by construction
    int t = threadIdx.x;
    if (t < 64) cnt[t] = 0;
    __syncthreads();
    for (int i = t; i < m; i += 256) {
        int2 p = pairs[s + i];
        buf[i] = p;
        atomicAdd(&cnt[p.x >> 18], 1);
    }
    __syncthreads();
    if (t < 64) {                           // one wave: scan 64 counters
        int v = cnt[t];
        int incl = v;
        #pragma unroll
        for (int o = 1; o < 64; o <<= 1) {
            int u = __shfl_up(incl, o);
            if (t >= o) incl += u;
        }
        cur[t] = incl - v;
        int n = (b << 6) + t;
        if (n < N_NODES_C) rowptr[n] = s + incl - v;
    }
    __syncthreads();
    for (int i = t; i < m; i += 256) {
        int2 p = buf[i];
        int dst = atomicAdd(&cur[p.x >> 18], 1);
        obuf[dst] = make_int2(p.x & 0x3FFFF, p.y);
    }
    __syncthreads();
    for (int i = t; i < m; i += 256)
        pairs[s + i] = obuf[i];
}

// ---------------- CSR gather (round-3 design: one wave per row) ----------------
__global__ __launch_bounds__(256) void gather_k(
    const int* __restrict__ rowptr, const int2* __restrict__ pairs,
    const float* __restrict__ ego, float* __restrict__ side,
    float* __restrict__ egoc,
    const int* __restrict__ u, const int* __restrict__ it,
    int nrows, int batch)
{
    int gtid = blockIdx.x * blockDim.x + threadIdx.x;
    int wave = gtid >> 6;
    int lane = threadIdx.x & 63;
    if (wave >= nrows) return;
    int r = wave;
    int n = u ? ((r < batch) ? u[r] : N_USERS_C + it[r - batch]) : r;
    int s  = rowptr[n];
    int ep = rowptr[n + 1];

    float acc = 0.0f;
    for (int base = s; base < ep; base += 64) {
        int2 p = make_int2(0, 0);
        if (base + lane < ep) p = pairs[base + lane];
        int cnt4 = (min(ep - base, 64) + 3) & ~3;
        for (int j = 0; j < cnt4; j += 4) {
            int c0 = __shfl(p.x, j + 0);
            int c1 = __shfl(p.x, j + 1);
            int c2 = __shfl(p.x, j + 2);
            int c3 = __shfl(p.x, j + 3);
            float v0 = __int_as_float(__shfl(p.y, j + 0));
            float v1 = __int_as_float(__shfl(p.y, j + 1));
            float v2 = __int_as_float(__shfl(p.y, j + 2));
            float v3 = __int_as_float(__shfl(p.y, j + 3));
            float f0 = ego[(size_t)c0 * D + lane];
            float f1 = ego[(size_t)c1 * D + lane];
            float f2 = ego[(size_t)c2 * D + lane];
            float f3 = ego[(size_t)c3 * D + lane];
            acc = fmaf(v0, f0, acc);
            acc = fmaf(v1, f1, acc);
            acc = fmaf(v2, f2, acc);
            acc = fmaf(v3, f3, acc);
        }
    }
    side[(size_t)r * D + lane] = acc;
    if (egoc) egoc[(size_t)r * D + lane] = ego[(size_t)n * D + lane];
}

// ---------------- Tiled transform ----------------
__global__ __launch_bounds__(256) void transform_k(
    const float* __restrict__ S, const float* __restrict__ E,
    const float* __restrict__ Wg, const float* __restrict__ bg,
    const float* __restrict__ Wb, const float* __restrict__ bb,
    float* __restrict__ out, int nrows)
{
    __shared__ __align__(16) float sWg[D * D];
    __shared__ __align__(16) float sWb[D * D];
    __shared__ __align__(16) float sAT[D][SPAD];
    __shared__ __align__(16) float sBT[D][SPAD];

    int t  = threadIdx.x;
    int tc = t & 15;
    int tr = t >> 4;
    int r0 = blockIdx.x * 64;

    for (int i = t; i < D * D; i += 256) {
        sWg[i] = Wg[i];
        sWb[i] = Wb[i];
    }
    for (int itr = 0; itr < 4; ++itr) {
        int rr  = itr * 16 + (t >> 4);
        int row = r0 + rr;
        float4 sv = make_float4(0.f, 0.f, 0.f, 0.f);
        float4 ev = sv;
        if (row < nrows) {
            sv = *(const float4*)&S[(size_t)row * D + tc * 4];
            ev = *(const float4*)&E[(size_t)row * D + tc * 4];
        }
        sAT[tc * 4 + 0][rr] = sv.x;
        sAT[tc * 4 + 1][rr] = sv.y;
        sAT[tc * 4 + 2][rr] = sv.z;
        sAT[tc * 4 + 3][rr] = sv.w;
        sBT[tc * 4 + 0][rr] = sv.x * ev.x;
        sBT[tc * 4 + 1][rr] = sv.y * ev.y;
        sBT[tc * 4 + 2][rr] = sv.z * ev.z;
        sBT[tc * 4 + 3][rr] = sv.w * ev.w;
    }
    __syncthreads();

    float acc[4][4] = {};
    for (int k = 0; k < D; ++k) {
        float4 a4 = *(const float4*)&sAT[k][tr * 4];
        float4 b4 = *(const float4*)&sBT[k][tr * 4];
        float4 g4 = *(const float4*)&sWg[k * D + tc * 4];
        float4 w4 = *(const float4*)&sWb[k * D + tc * 4];
        float av[4] = {a4.x, a4.y, a4.z, a4.w};
        float bv[4] = {b4.x, b4.y, b4.z, b4.w};
        float gv[4] = {g4.x, g4.y, g4.z, g4.w};
        float wv[4] = {w4.x, w4.y, w4.z, w4.w};
        #pragma unroll
        for (int i = 0; i < 4; ++i)
            #pragma unroll
            for (int j = 0; j < 4; ++j)
                acc[i][j] = fmaf(av[i], gv[j], fmaf(bv[i], wv[j], acc[i][j]));
    }

    float4 bgv = *(const float4*)&bg[tc * 4];
    float4 bbv = *(const float4*)&bb[tc * 4];
    float bias[4] = {bgv.x + bbv.x, bgv.y + bbv.y, bgv.z + bbv.z, bgv.w + bbv.w};

    float vv[4][4];
    float ss[4] = {0.f, 0.f, 0.f, 0.f};
    #pragma unroll
    for (int i = 0; i < 4; ++i) {
        #pragma unroll
        for (int j = 0; j < 4; ++j) {
            float v = acc[i][j] + bias[j];
            v = (v > 0.0f) ? v : 0.2f * v;
            vv[i][j] = v;
            ss[i] += v * v;
        }
    }
    #pragma unroll
    for (int i = 0; i < 4; ++i) {
        #pragma unroll
        for (int off = 1; off < 16; off <<= 1)
            ss[i] += __shfl_xor(ss[i], off);
    }
    #pragma unroll
    for (int i = 0; i < 4; ++i) {
        int row = r0 + tr * 4 + i;
        if (row < nrows) {
            float inv = 1.0f / fmaxf(sqrtf(ss[i]), 1e-12f);
            float4 o = make_float4(vv[i][0] * inv, vv[i][1] * inv,
                                   vv[i][2] * inv, vv[i][3] * inv);
            *(float4*)&out[(size_t)row * D + tc * 4] = o;
        }
    }
}

// ---------------- Readout ----------------
__global__ __launch_bounds__(256) void gamma_k(
    const float* __restrict__ x, const float* __restrict__ e1,
    const float* __restrict__ e2c, const int* __restrict__ users,
    const int* __restrict__ items, float* __restrict__ gamma, int batch)
{
    int gtid = blockIdx.x * blockDim.x + threadIdx.x;
    int wave = gtid >> 6;
    int lane = threadIdx.x & 63;
    if (wave >= batch) return;
    size_t uu = (size_t)users[wave];
    size_t tt = (size_t)(N_USERS_C + items[wave]);
    float acc = x[uu * D + lane] * x[tt * D + lane]
              + e1[uu * D + lane] * e1[tt * D + lane]
              + e2c[(size_t)wave * D + lane] * e2c[(size_t)(batch + wave) * D + lane];
    #pragma unroll
    for (int off = 1; off < 64; off <<= 1) acc += __shfl_xor(acc, off);
    if (lane == 0) gamma[wave] = acc;
}

extern "C" void kernel_launch(void* const* d_in, const int* in_sizes, int n_in,
                              void* d_out, int out_size, void* d_ws, size_t ws_size,
                              hipStream_t stream) {
    const int*   rows  = (const int*)d_in[0];
    const int*   cols  = (const int*)d_in[1];
    const float* vals  = (const float*)d_in[2];
    const float* x     = (const float*)d_in[3];
    const int*   users = (const int*)d_in[4];
    const int*   items = (const int*)d_in[5];
    const float* Wg0 = (const float*)d_in[6];
    const float* bg0 = (const float*)d_in[7];
    const float* Wb0 = (const float*)d_in[8];
    const float* bb0 = (const float*)d_in[9];
    const float* Wg1 = (const float*)d_in[10];
    const float* bg1 = (const float*)d_in[11];
    const float* Wb1 = (const float*)d_in[12];
    const float* bb1 = (const float*)d_in[13];

    int nnz   = in_sizes[0];
    int batch = in_sizes[4];
    float* out = (float*)d_out;

    size_t emb = (size_t)N_NODES_C * D;
    float* A       = (float*)d_ws;                 // e1 [150k x 64]
    float* Sbuf    = A + emb;                      // side; reused for layer-2 compacts
    int*   bstart  = (int*)(Sbuf + emb);           // NB+1 (+1 pad)
    int*   bcountP = bstart + (NB + 2);
    int*   bcur    = bcountP + NB * CPAD;
    int*   rowptr  = bcur + NB * CPAD;             // N+1 (+1 pad)
    int2*  pairs   = (int2*)(rowptr + N_NODES_C + 2);

    float* side2c = Sbuf;                          // [2B x 64]
    float* egoc   = Sbuf + (size_t)2 * 2048 * D;
    float* e2c    = egoc + (size_t)2 * 2048 * D;

    // --- bucket CSR build ---
    hipMemsetAsync(bcountP, 0, NB * CPAD * sizeof(int), stream);
    histb_k<<<256, 256, 0, stream>>>(rows, bcountP, nnz);
    scanb_k<<<1, 1024, 0, stream>>>(bcountP, bstart, NB);
    initcur_k<<<(NB + 255) / 256, 256, 0, stream>>>(bstart, bcur, rowptr, NB, nnz);
    fillb_k<<<512, 256, 0, stream>>>(rows, cols, vals, bcur, pairs, nnz);
    sortb_k<<<NB, 256, 0, stream>>>(bstart, pairs, rowptr);

    // --- Layer 1 (all nodes) ---
    gather_k<<<(N_NODES_C * 64 + 255) / 256, 256, 0, stream>>>(
        rowptr, pairs, x, Sbuf, nullptr, nullptr, nullptr, N_NODES_C, 0);
    transform_k<<<(N_NODES_C + 63) / 64, 256, 0, stream>>>(
        Sbuf, x, Wg0, bg0, Wb0, bb0, A, N_NODES_C);

    // --- Layer 2 (sampled 2*batch rows) ---
    gather_k<<<(2 * batch * 64 + 255) / 256, 256, 0, stream>>>(
        rowptr, pairs, A, side2c, egoc, users, items, 2 * batch, batch);
    transform_k<<<(2 * batch + 63) / 64, 256, 0, stream>>>(
        side2c, egoc, Wg1, bg1, Wb1, bb1, e2c, 2 * batch);

    // --- Readout ---
    gamma_k<<<(batch * 64 + 255) / 256, 256, 0, stream>>>(
        x, A, e2c, users, items, out, batch);
}

// Round 6
// 387.459 us; speedup vs baseline: 3.2590x; 1.1522x over previous
//
#include <hip/hip_runtime.h>

#define N_USERS_C 100000
#define N_NODES_C 150000
#define D 64
#define NB 2344              // ceil(150000/64) fine buckets (64 rows)
#define NSUP 74              // ceil(150000/2048) super buckets (2048 rows = 32 fine)
#define CPAD 16              // global cursor padding: 1 int per 64B line
#define SPAD 68              // transform transposed-tile row stride
#define BCAP 2048            // per-fine-bucket LDS sort capacity (mean 1024, sigma 32)
#define S1CAP 4704           // S1 per-block chunk capacity (chunk = 4688)
#define S2CAP 5120           // S2 per-block chunk capacity (mean ~4096)
#define BPS 8                // blocks per super in S2

// ---------------- Fused fine+super histogram (LDS-privatized) ----------------
__global__ __launch_bounds__(256) void histb2_k(
    const int* __restrict__ rows, int* __restrict__ bcountP,
    int* __restrict__ scountP, int nnz)
{
    __shared__ int lh[NB];
    for (int i = threadIdx.x; i < NB; i += 256) lh[i] = 0;
    __syncthreads();
    int gtid = blockIdx.x * blockDim.x + threadIdx.x;
    int stride = gridDim.x * blockDim.x;
    for (int e = gtid; e < nnz; e += stride)
        atomicAdd(&lh[rows[e] >> 6], 1);
    __syncthreads();
    for (int b = threadIdx.x; b < NB; b += 256) {
        int c = lh[b];
        if (c) atomicAdd(&bcountP[b * CPAD], c);
    }
    for (int sp = threadIdx.x; sp < NSUP; sp += 256) {
        int hi = min(sp * 32 + 32, NB);
        int c = 0;
        for (int b = sp * 32; b < hi; ++b) c += lh[b];
        if (c) atomicAdd(&scountP[sp * CPAD], c);
    }
}

// ---------------- Single-block exclusive scan over padded counts ----------------
__global__ __launch_bounds__(1024) void scanb_k(
    const int* __restrict__ cntP, int* __restrict__ start, int n)
{
    __shared__ int wsum[16];
    __shared__ int woff[16];
    __shared__ int carry;
    __shared__ int tile_total;
    int lane = threadIdx.x & 63;
    int wid  = threadIdx.x >> 6;
    if (threadIdx.x == 0) carry = 0;
    __syncthreads();
    for (int base = 0; base < n; base += 1024) {
        int i = base + (int)threadIdx.x;
        int v = (i < n) ? cntP[i * CPAD] : 0;
        int incl = v;
        #pragma unroll
        for (int off = 1; off < 64; off <<= 1) {
            int t = __shfl_up(incl, off);
            if (lane >= off) incl += t;
        }
        if (lane == 63) wsum[wid] = incl;
        __syncthreads();
        if (threadIdx.x == 0) {
            int run = 0;
            #pragma unroll
            for (int w = 0; w < 16; ++w) { int t = wsum[w]; woff[w] = run; run += t; }
            tile_total = run;
        }
        __syncthreads();
        if (i < n) start[i] = carry + woff[wid] + incl - v;
        __syncthreads();
        if (threadIdx.x == 0) carry += tile_total;
    }
    __syncthreads();
    if (threadIdx.x == 0) start[n] = carry;
}

// cursors = starts (padded); rowptr[N] = nnz.
__global__ __launch_bounds__(256) void initcur2_k(
    const int* __restrict__ bstart, int* __restrict__ bcur,
    const int* __restrict__ sstart, int* __restrict__ scur,
    int* __restrict__ rowptr, int nnz)
{
    int i = blockIdx.x * blockDim.x + threadIdx.x;
    if (i < NB) bcur[i * CPAD] = bstart[i];
    if (i < NSUP) scur[i * CPAD] = sstart[i];
    if (i == 0) rowptr[N_NODES_C] = nnz;
}

// ---------------- S1: scatter into 74 super-buckets, LDS-staged runs ----------------
// pairs1[p].x = ((row & 2047) << 18) | col ; super = row >> 11.
__global__ __launch_bounds__(256) void s1_k(
    const int* __restrict__ rows, const int* __restrict__ cols,
    const float* __restrict__ vals, int* __restrict__ scurP,
    int2* __restrict__ pairs1, int nnz)
{
    __shared__ int2 sbuf[S1CAP];
    __shared__ unsigned char smap[S1CAP];
    __shared__ int lcnt[NSUP], lofs[NSUP], lcur[NSUP], gb[NSUP];
    int t = threadIdx.x;
    for (int i = t; i < NSUP; i += 256) lcnt[i] = 0;
    __syncthreads();
    int per = (nnz + gridDim.x - 1) / gridDim.x;
    int s = blockIdx.x * per;
    int e = min(nnz, s + per);
    for (int i = s + t; i < e; i += 256)
        atomicAdd(&lcnt[rows[i] >> 11], 1);
    __syncthreads();
    if (t == 0) {
        int run = 0;
        for (int i = 0; i < NSUP; ++i) { lofs[i] = run; run += lcnt[i]; }
    }
    __syncthreads();
    for (int i = t; i < NSUP; i += 256) {
        int c = lcnt[i];
        gb[i] = c ? atomicAdd(&scurP[i * CPAD], c) : 0;
        lcur[i] = lofs[i];
    }
    __syncthreads();
    for (int i = s + t; i < e; i += 256) {
        int r = rows[i];
        int sp = r >> 11;
        int dst = atomicAdd(&lcur[sp], 1);
        sbuf[dst] = make_int2(((r & 2047) << 18) | cols[i], __float_as_int(vals[i]));
        smap[dst] = (unsigned char)sp;
    }
    __syncthreads();
    int m = e - s;
    for (int i = t; i < m; i += 256) {
        int sp = smap[i];
        pairs1[gb[sp] + (i - lofs[sp])] = sbuf[i];
    }
}

// ---------------- S2: scatter supers into 64-row fine buckets, LDS-staged ----------------
// output pairs[p].x = ((row & 63) << 18) | col, fine-bucket-grouped.
__global__ __launch_bounds__(256) void s2_k(
    const int* __restrict__ sstart, const int2* __restrict__ pairs1,
    int* __restrict__ bcurP, int2* __restrict__ pairs)
{
    __shared__ int2 sbuf[S2CAP];
    __shared__ unsigned char fmap[S2CAP];
    __shared__ int fcnt[32], fofs[32], fcur[32], gb[32];
    int sp = blockIdx.x / BPS, part = blockIdx.x % BPS;
    int lo = sstart[sp], hi = sstart[sp + 1];
    int len = hi - lo;
    int per = (len + BPS - 1) / BPS;
    int cs = lo + part * per;
    int ce = min(hi, cs + per);
    int m = ce - cs;
    if (m <= 0) return;                      // uniform across block
    int t = threadIdx.x;
    if (t < 32) fcnt[t] = 0;
    __syncthreads();
    for (int i = t; i < m; i += 256)
        atomicAdd(&fcnt[(pairs1[cs + i].x >> 18) >> 6], 1);
    __syncthreads();
    if (t < 32) {
        int v = fcnt[t], incl = v;
        #pragma unroll
        for (int o = 1; o < 32; o <<= 1) {
            int u = __shfl_up(incl, o);
            if (t >= o) incl += u;
        }
        fofs[t] = incl - v;
        fcur[t] = incl - v;
        gb[t] = v ? atomicAdd(&bcurP[(sp * 32 + t) * CPAD], v) : 0;
    }
    __syncthreads();
    for (int i = t; i < m; i += 256) {
        int2 p = pairs1[cs + i];
        int ris = p.x >> 18;                 // row-in-super (11 bits)
        int f = ris >> 6;
        int dst = atomicAdd(&fcur[f], 1);
        sbuf[dst] = make_int2(((ris & 63) << 18) | (p.x & 0x3FFFF), p.y);
        fmap[dst] = (unsigned char)f;
    }
    __syncthreads();
    for (int i = t; i < m; i += 256) {
        int f = fmap[i];
        pairs[gb[f] + (i - fofs[f])] = sbuf[i];
    }
}

// ---------------- Per-bucket LDS counting sort -> exact CSR ----------------
__global__ __launch_bounds__(256) void sortb_k(
    const int* __restrict__ bstart, int2* __restrict__ pairs,
    int* __restrict__ rowptr)
{
    __shared__ int2 buf[BCAP];
    __shared__ int2 obuf[BCAP];
    __shared__ int cnt[64];
    __shared__ int cur[64];
    int b = blockIdx.x;
    int s = bstart[b], e = bstart[b + 1];
    int m = e - s;
    int t = threadIdx.x;
    if (t < 64) cnt[t] = 0;
    __syncthreads();
    for (int i = t; i < m; i += 256) {
        int2 p = pairs[s + i];
        buf[i] = p;
        atomicAdd(&cnt[p.x >> 18], 1);
    }
    __syncthreads();
    if (t < 64) {
        int v = cnt[t];
        int incl = v;
        #pragma unroll
        for (int o = 1; o < 64; o <<= 1) {
            int u = __shfl_up(incl, o);
            if (t >= o) incl += u;
        }
        cur[t] = incl - v;
        int n = (b << 6) + t;
        if (n < N_NODES_C) rowptr[n] = s + incl - v;
    }
    __syncthreads();
    for (int i = t; i < m; i += 256) {
        int2 p = buf[i];
        int dst = atomicAdd(&cur[p.x >> 18], 1);
        obuf[dst] = make_int2(p.x & 0x3FFFF, p.y);
    }
    __syncthreads();
    for (int i = t; i < m; i += 256)
        pairs[s + i] = obuf[i];
}

// ---------------- CSR gather: one wave per row ----------------
__global__ __launch_bounds__(256) void gather_k(
    const int* __restrict__ rowptr, const int2* __restrict__ pairs,
    const float* __restrict__ ego, float* __restrict__ side,
    float* __restrict__ egoc,
    const int* __restrict__ u, const int* __restrict__ it,
    int nrows, int batch)
{
    int gtid = blockIdx.x * blockDim.x + threadIdx.x;
    int wave = gtid >> 6;
    int lane = threadIdx.x & 63;
    if (wave >= nrows) return;
    int r = wave;
    int n = u ? ((r < batch) ? u[r] : N_USERS_C + it[r - batch]) : r;
    int s  = rowptr[n];
    int ep = rowptr[n + 1];

    float acc = 0.0f;
    for (int base = s; base < ep; base += 64) {
        int2 p = make_int2(0, 0);
        if (base + lane < ep) p = pairs[base + lane];
        int cnt4 = (min(ep - base, 64) + 3) & ~3;
        for (int j = 0; j < cnt4; j += 4) {
            int c0 = __shfl(p.x, j + 0);
            int c1 = __shfl(p.x, j + 1);
            int c2 = __shfl(p.x, j + 2);
            int c3 = __shfl(p.x, j + 3);
            float v0 = __int_as_float(__shfl(p.y, j + 0));
            float v1 = __int_as_float(__shfl(p.y, j + 1));
            float v2 = __int_as_float(__shfl(p.y, j + 2));
            float v3 = __int_as_float(__shfl(p.y, j + 3));
            float f0 = ego[(size_t)c0 * D + lane];
            float f1 = ego[(size_t)c1 * D + lane];
            float f2 = ego[(size_t)c2 * D + lane];
            float f3 = ego[(size_t)c3 * D + lane];
            acc = fmaf(v0, f0, acc);
            acc = fmaf(v1, f1, acc);
            acc = fmaf(v2, f2, acc);
            acc = fmaf(v3, f3, acc);
        }
    }
    side[(size_t)r * D + lane] = acc;
    if (egoc) egoc[(size_t)r * D + lane] = ego[(size_t)n * D + lane];
}

// ---------------- Tiled transform ----------------
__global__ __launch_bounds__(256) void transform_k(
    const float* __restrict__ S, const float* __restrict__ E,
    const float* __restrict__ Wg, const float* __restrict__ bg,
    const float* __restrict__ Wb, const float* __restrict__ bb,
    float* __restrict__ out, int nrows)
{
    __shared__ __align__(16) float sWg[D * D];
    __shared__ __align__(16) float sWb[D * D];
    __shared__ __align__(16) float sAT[D][SPAD];
    __shared__ __align__(16) float sBT[D][SPAD];

    int t  = threadIdx.x;
    int tc = t & 15;
    int tr = t >> 4;
    int r0 = blockIdx.x * 64;

    for (int i = t; i < D * D; i += 256) {
        sWg[i] = Wg[i];
        sWb[i] = Wb[i];
    }
    for (int itr = 0; itr < 4; ++itr) {
        int rr  = itr * 16 + (t >> 4);
        int row = r0 + rr;
        float4 sv = make_float4(0.f, 0.f, 0.f, 0.f);
        float4 ev = sv;
        if (row < nrows) {
            sv = *(const float4*)&S[(size_t)row * D + tc * 4];
            ev = *(const float4*)&E[(size_t)row * D + tc * 4];
        }
        sAT[tc * 4 + 0][rr] = sv.x;
        sAT[tc * 4 + 1][rr] = sv.y;
        sAT[tc * 4 + 2][rr] = sv.z;
        sAT[tc * 4 + 3][rr] = sv.w;
        sBT[tc * 4 + 0][rr] = sv.x * ev.x;
        sBT[tc * 4 + 1][rr] = sv.y * ev.y;
        sBT[tc * 4 + 2][rr] = sv.z * ev.z;
        sBT[tc * 4 + 3][rr] = sv.w * ev.w;
    }
    __syncthreads();

    float acc[4][4] = {};
    for (int k = 0; k < D; ++k) {
        float4 a4 = *(const float4*)&sAT[k][tr * 4];
        float4 b4 = *(const float4*)&sBT[k][tr * 4];
        float4 g4 = *(const float4*)&sWg[k * D + tc * 4];
        float4 w4 = *(const float4*)&sWb[k * D + tc * 4];
        float av[4] = {a4.x, a4.y, a4.z, a4.w};
        float bv[4] = {b4.x, b4.y, b4.z, b4.w};
        float gv[4] = {g4.x, g4.y, g4.z, g4.w};
        float wv[4] = {w4.x, w4.y, w4.z, w4.w};
        #pragma unroll
        for (int i = 0; i < 4; ++i)
            #pragma unroll
            for (int j = 0; j < 4; ++j)
                acc[i][j] = fmaf(av[i], gv[j], fmaf(bv[i], wv[j], acc[i][j]));
    }

    float4 bgv = *(const float4*)&bg[tc * 4];
    float4 bbv = *(const float4*)&bb[tc * 4];
    float bias[4] = {bgv.x + bbv.x, bgv.y + bbv.y, bgv.z + bbv.z, bgv.w + bbv.w};

    float vv[4][4];
    float ss[4] = {0.f, 0.f, 0.f, 0.f};
    #pragma unroll
    for (int i = 0; i < 4; ++i) {
        #pragma unroll
        for (int j = 0; j < 4; ++j) {
            float v = acc[i][j] + bias[j];
            v = (v > 0.0f) ? v : 0.2f * v;
            vv[i][j] = v;
            ss[i] += v * v;
        }
    }
    #pragma unroll
    for (int i = 0; i < 4; ++i) {
        #pragma unroll
        for (int off = 1; off < 16; off <<= 1)
            ss[i] += __shfl_xor(ss[i], off);
    }
    #pragma unroll
    for (int i = 0; i < 4; ++i) {
        int row = r0 + tr * 4 + i;
        if (row < nrows) {
            float inv = 1.0f / fmaxf(sqrtf(ss[i]), 1e-12f);
            float4 o = make_float4(vv[i][0] * inv, vv[i][1] * inv,
                                   vv[i][2] * inv, vv[i][3] * inv);
            *(float4*)&out[(size_t)row * D + tc * 4] = o;
        }
    }
}

// ---------------- Readout ----------------
__global__ __launch_bounds__(256) void gamma_k(
    const float* __restrict__ x, const float* __restrict__ e1,
    const float* __restrict__ e2c, const int* __restrict__ users,
    const int* __restrict__ items, float* __restrict__ gamma, int batch)
{
    int gtid = blockIdx.x * blockDim.x + threadIdx.x;
    int wave = gtid >> 6;
    int lane = threadIdx.x & 63;
    if (wave >= batch) return;
    size_t uu = (size_t)users[wave];
    size_t tt = (size_t)(N_USERS_C + items[wave]);
    float acc = x[uu * D + lane] * x[tt * D + lane]
              + e1[uu * D + lane] * e1[tt * D + lane]
              + e2c[(size_t)wave * D + lane] * e2c[(size_t)(batch + wave) * D + lane];
    #pragma unroll
    for (int off = 1; off < 64; off <<= 1) acc += __shfl_xor(acc, off);
    if (lane == 0) gamma[wave] = acc;
}

extern "C" void kernel_launch(void* const* d_in, const int* in_sizes, int n_in,
                              void* d_out, int out_size, void* d_ws, size_t ws_size,
                              hipStream_t stream) {
    const int*   rows  = (const int*)d_in[0];
    const int*   cols  = (const int*)d_in[1];
    const float* vals  = (const float*)d_in[2];
    const float* x     = (const float*)d_in[3];
    const int*   users = (const int*)d_in[4];
    const int*   items = (const int*)d_in[5];
    const float* Wg0 = (const float*)d_in[6];
    const float* bg0 = (const float*)d_in[7];
    const float* Wb0 = (const float*)d_in[8];
    const float* bb0 = (const float*)d_in[9];
    const float* Wg1 = (const float*)d_in[10];
    const float* bg1 = (const float*)d_in[11];
    const float* Wb1 = (const float*)d_in[12];
    const float* bb1 = (const float*)d_in[13];

    int nnz   = in_sizes[0];
    int batch = in_sizes[4];
    float* out = (float*)d_out;

    size_t emb = (size_t)N_NODES_C * D;
    float* A       = (float*)d_ws;                 // e1 [150k x 64]
    float* Sbuf    = A + emb;                      // side; aliases pairs1 during build
    int*   bstart  = (int*)(Sbuf + emb);           // NB+1 (+pad)
    int*   sstart  = bstart + (NB + 2);            // NSUP+1 (+pad)
    int*   bcountP = sstart + (NSUP + 2);
    int*   scountP = bcountP + NB * CPAD;          // contiguous for one memset
    int*   bcur    = scountP + NSUP * CPAD;
    int*   scur    = bcur + NB * CPAD;
    int*   rowptr  = scur + NSUP * CPAD;           // N+1 (+pad)
    int2*  pairs   = (int2*)(rowptr + N_NODES_C + 2);

    int2*  pairs1 = (int2*)Sbuf;                   // build-time only (19.2 MB < 38.4 MB)
    float* side2c = Sbuf;                          // layer-2 compacts (after build)
    float* egoc   = Sbuf + (size_t)2 * 2048 * D;
    float* e2c    = egoc + (size_t)2 * 2048 * D;

    // --- two-level bucket build ---
    hipMemsetAsync(bcountP, 0, (NB + NSUP) * CPAD * sizeof(int), stream);
    histb2_k<<<256, 256, 0, stream>>>(rows, bcountP, scountP, nnz);
    scanb_k<<<1, 1024, 0, stream>>>(bcountP, bstart, NB);
    scanb_k<<<1, 1024, 0, stream>>>(scountP, sstart, NSUP);
    initcur2_k<<<(NB + 255) / 256, 256, 0, stream>>>(bstart, bcur, sstart, scur, rowptr, nnz);
    int g1 = (nnz + 4687) / 4688;                  // chunk 4688 <= S1CAP
    s1_k<<<g1, 256, 0, stream>>>(rows, cols, vals, scur, pairs1, nnz);
    s2_k<<<NSUP * BPS, 256, 0, stream>>>(sstart, pairs1, bcur, pairs);
    sortb_k<<<NB, 256, 0, stream>>>(bstart, pairs, rowptr);

    // --- Layer 1 (all nodes) ---
    gather_k<<<(N_NODES_C * 64 + 255) / 256, 256, 0, stream>>>(
        rowptr, pairs, x, Sbuf, nullptr, nullptr, nullptr, N_NODES_C, 0);
    transform_k<<<(N_NODES_C + 63) / 64, 256, 0, stream>>>(
        Sbuf, x, Wg0, bg0, Wb0, bb0, A, N_NODES_C);

    // --- Layer 2 (sampled 2*batch rows) ---
    gather_k<<<(2 * batch * 64 + 255) / 256, 256, 0, stream>>>(
        rowptr, pairs, A, side2c, egoc, users, items, 2 * batch, batch);
    transform_k<<<(2 * batch + 63) / 64, 256, 0, stream>>>(
        side2c, egoc, Wg1, bg1, Wb1, bb1, e2c, 2 * batch);

    // --- Readout ---
    gamma_k<<<(batch * 64 + 255) / 256, 256, 0, stream>>>(
        x, A, e2c, users, items, out, batch);
}

// Round 7
// 338.805 us; speedup vs baseline: 3.7270x; 1.1436x over previous
//
#include <hip/hip_runtime.h>

#define N_USERS_C 100000
#define N_NODES_C 150000
#define D 64
#define NB 2344              // ceil(150000/64) fine buckets (compact-row space)
#define NSUP 74              // ceil(150000/2048) super buckets
#define CPAD 16              // global cursor padding: 1 int per 64B line
#define SPAD 68              // transform transposed-tile row stride
#define BCAP 2048            // per-fine-bucket LDS sort capacity
#define S1CAP 4704           // S1 per-block chunk capacity
#define S2CAP 5120           // S2 per-block chunk capacity
#define BPS 8                // blocks per super in S2

// ---------------- Needed-set marking ----------------
__global__ __launch_bounds__(256) void mark1_k(
    const int* __restrict__ u, const int* __restrict__ it,
    unsigned char* __restrict__ samp, unsigned char* __restrict__ need, int batch)
{
    int i = blockIdx.x * blockDim.x + threadIdx.x;
    if (i >= 2 * batch) return;
    int n = (i < batch) ? u[i] : N_USERS_C + it[i - batch];
    samp[n] = 1;
    need[n] = 1;
}

__global__ __launch_bounds__(256) void mark2_k(
    const int* __restrict__ rows, const int* __restrict__ cols,
    const unsigned char* __restrict__ samp, unsigned char* __restrict__ need, int nnz)
{
    int gtid = blockIdx.x * blockDim.x + threadIdx.x;
    int stride = gridDim.x * blockDim.x;
    for (int e = gtid; e < nnz; e += stride)
        if (samp[rows[e]]) need[cols[e]] = 1;
}

// ---------------- 3-kernel scan over need flags -> idx / list / M ----------------
__global__ __launch_bounds__(1024) void scan1_k(
    const unsigned char* __restrict__ need, int* __restrict__ part,
    int* __restrict__ bsum, int n)
{
    __shared__ int wsum[16];
    int i = blockIdx.x * 1024 + threadIdx.x;
    int lane = threadIdx.x & 63, wid = threadIdx.x >> 6;
    int v = (i < n) ? (int)need[i] : 0;
    int incl = v;
    #pragma unroll
    for (int off = 1; off < 64; off <<= 1) {
        int t = __shfl_up(incl, off);
        if (lane >= off) incl += t;
    }
    if (lane == 63) wsum[wid] = incl;
    __syncthreads();
    int woff = 0;
    for (int w = 0; w < wid; ++w) woff += wsum[w];
    if (i < n) part[i] = woff + incl - v;
    if (threadIdx.x == 1023) bsum[blockIdx.x] = woff + incl;
}

__global__ __launch_bounds__(1024) void scan2_k(
    int* __restrict__ bsum, int nb, int* __restrict__ Mptr)
{
    __shared__ int wsum[16];
    int lane = threadIdx.x & 63, wid = threadIdx.x >> 6;
    int i = threadIdx.x;
    int v = (i < nb) ? bsum[i] : 0;
    int incl = v;
    #pragma unroll
    for (int off = 1; off < 64; off <<= 1) {
        int t = __shfl_up(incl, off);
        if (lane >= off) incl += t;
    }
    if (lane == 63) wsum[wid] = incl;
    __syncthreads();
    int woff = 0;
    for (int w = 0; w < wid; ++w) woff += wsum[w];
    if (i < nb) bsum[i] = woff + incl - v;
    if (i == nb - 1) Mptr[0] = woff + incl;
}

// idx[n] = compact index if needed else -1 ; list[compact] = n
__global__ __launch_bounds__(256) void scan3_k(
    const int* __restrict__ bsum, int* __restrict__ idx,
    const unsigned char* __restrict__ need, int* __restrict__ list, int n)
{
    int i = blockIdx.x * blockDim.x + threadIdx.x;
    if (i >= n) return;
    int t = idx[i] + bsum[i >> 10];
    if (need[i]) { idx[i] = t; list[t] = i; }
    else idx[i] = -1;
}

// ---------------- Fused fine+super histogram over needed edges (compact space) ----------------
__global__ __launch_bounds__(256) void histc_k(
    const int* __restrict__ rows, const int* __restrict__ idx,
    int* __restrict__ bcountP, int* __restrict__ scountP, int nnz)
{
    __shared__ int lh[NB];
    for (int i = threadIdx.x; i < NB; i += 256) lh[i] = 0;
    __syncthreads();
    int gtid = blockIdx.x * blockDim.x + threadIdx.x;
    int stride = gridDim.x * blockDim.x;
    for (int e = gtid; e < nnz; e += stride) {
        int ci = idx[rows[e]];
        if (ci >= 0) atomicAdd(&lh[ci >> 6], 1);
    }
    __syncthreads();
    for (int b = threadIdx.x; b < NB; b += 256) {
        int c = lh[b];
        if (c) atomicAdd(&bcountP[b * CPAD], c);
    }
    for (int sp = threadIdx.x; sp < NSUP; sp += 256) {
        int hi = min(sp * 32 + 32, NB);
        int c = 0;
        for (int b = sp * 32; b < hi; ++b) c += lh[b];
        if (c) atomicAdd(&scountP[sp * CPAD], c);
    }
}

// ---------------- Single-block exclusive scan over padded counts ----------------
__global__ __launch_bounds__(1024) void scanb_k(
    const int* __restrict__ cntP, int* __restrict__ start, int n)
{
    __shared__ int wsum[16];
    __shared__ int woff[16];
    __shared__ int carry;
    __shared__ int tile_total;
    int lane = threadIdx.x & 63;
    int wid  = threadIdx.x >> 6;
    if (threadIdx.x == 0) carry = 0;
    __syncthreads();
    for (int base = 0; base < n; base += 1024) {
        int i = base + (int)threadIdx.x;
        int v = (i < n) ? cntP[i * CPAD] : 0;
        int incl = v;
        #pragma unroll
        for (int off = 1; off < 64; off <<= 1) {
            int t = __shfl_up(incl, off);
            if (lane >= off) incl += t;
        }
        if (lane == 63) wsum[wid] = incl;
        __syncthreads();
        if (threadIdx.x == 0) {
            int run = 0;
            #pragma unroll
            for (int w = 0; w < 16; ++w) { int t = wsum[w]; woff[w] = run; run += t; }
            tile_total = run;
        }
        __syncthreads();
        if (i < n) start[i] = carry + woff[wid] + incl - v;
        __syncthreads();
        if (threadIdx.x == 0) carry += tile_total;
    }
    __syncthreads();
    if (threadIdx.x == 0) start[n] = carry;
}

// cursors = starts; rowptr[M] = total needed edges.
__global__ __launch_bounds__(256) void initcur2_k(
    const int* __restrict__ bstart, int* __restrict__ bcur,
    const int* __restrict__ sstart, int* __restrict__ scur,
    int* __restrict__ rowptr, const int* __restrict__ Mptr)
{
    int i = blockIdx.x * blockDim.x + threadIdx.x;
    if (i < NB) bcur[i * CPAD] = bstart[i];
    if (i < NSUP) scur[i * CPAD] = sstart[i];
    if (i == 0) rowptr[Mptr[0]] = bstart[NB];
}

// ---------------- S1: needed edges -> 74 super-buckets (compact space) ----------------
// pairs1[p].x = ((crow & 2047) << 18) | col ; super = crow >> 11.
__global__ __launch_bounds__(256) void s1_k(
    const int* __restrict__ rows, const int* __restrict__ cols,
    const float* __restrict__ vals, const int* __restrict__ idx,
    int* __restrict__ scurP, int2* __restrict__ pairs1, int nnz)
{
    __shared__ int2 sbuf[S1CAP];
    __shared__ unsigned char smap[S1CAP];
    __shared__ int lcnt[NSUP], lofs[NSUP], lcur[NSUP], gb[NSUP];
    __shared__ int stot;
    int t = threadIdx.x;
    for (int i = t; i < NSUP; i += 256) lcnt[i] = 0;
    __syncthreads();
    int per = (nnz + gridDim.x - 1) / gridDim.x;
    int s = blockIdx.x * per;
    int e = min(nnz, s + per);
    for (int i = s + t; i < e; i += 256) {
        int ci = idx[rows[i]];
        if (ci >= 0) atomicAdd(&lcnt[ci >> 11], 1);
    }
    __syncthreads();
    if (t == 0) {
        int run = 0;
        for (int i = 0; i < NSUP; ++i) { lofs[i] = run; run += lcnt[i]; }
        stot = run;
    }
    __syncthreads();
    for (int i = t; i < NSUP; i += 256) {
        int c = lcnt[i];
        gb[i] = c ? atomicAdd(&scurP[i * CPAD], c) : 0;
        lcur[i] = lofs[i];
    }
    __syncthreads();
    for (int i = s + t; i < e; i += 256) {
        int ci = idx[rows[i]];
        if (ci < 0) continue;
        int sp = ci >> 11;
        int dst = atomicAdd(&lcur[sp], 1);
        sbuf[dst] = make_int2(((ci & 2047) << 18) | cols[i], __float_as_int(vals[i]));
        smap[dst] = (unsigned char)sp;
    }
    __syncthreads();
    int m = stot;
    for (int i = t; i < m; i += 256) {
        int sp = smap[i];
        pairs1[gb[sp] + (i - lofs[sp])] = sbuf[i];
    }
}

// ---------------- S2: supers -> 64-row fine buckets (compact space) ----------------
__global__ __launch_bounds__(256) void s2_k(
    const int* __restrict__ sstart, const int2* __restrict__ pairs1,
    int* __restrict__ bcurP, int2* __restrict__ pairs)
{
    __shared__ int2 sbuf[S2CAP];
    __shared__ unsigned char fmap[S2CAP];
    __shared__ int fcnt[32], fofs[32], fcur[32], gb[32];
    int sp = blockIdx.x / BPS, part = blockIdx.x % BPS;
    int lo = sstart[sp], hi = sstart[sp + 1];
    int len = hi - lo;
    int per = (len + BPS - 1) / BPS;
    int cs = lo + part * per;
    int ce = min(hi, cs + per);
    int m = ce - cs;
    if (m <= 0) return;
    int t = threadIdx.x;
    if (t < 32) fcnt[t] = 0;
    __syncthreads();
    for (int i = t; i < m; i += 256)
        atomicAdd(&fcnt[(pairs1[cs + i].x >> 18) >> 6], 1);
    __syncthreads();
    if (t < 32) {
        int v = fcnt[t], incl = v;
        #pragma unroll
        for (int o = 1; o < 32; o <<= 1) {
            int u = __shfl_up(incl, o);
            if (t >= o) incl += u;
        }
        fofs[t] = incl - v;
        fcur[t] = incl - v;
        gb[t] = v ? atomicAdd(&bcurP[(sp * 32 + t) * CPAD], v) : 0;
    }
    __syncthreads();
    for (int i = t; i < m; i += 256) {
        int2 p = pairs1[cs + i];
        int ris = p.x >> 18;
        int f = ris >> 6;
        int dst = atomicAdd(&fcur[f], 1);
        sbuf[dst] = make_int2(((ris & 63) << 18) | (p.x & 0x3FFFF), p.y);
        fmap[dst] = (unsigned char)f;
    }
    __syncthreads();
    for (int i = t; i < m; i += 256) {
        int f = fmap[i];
        pairs[gb[f] + (i - fofs[f])] = sbuf[i];
    }
}

// ---------------- Per-bucket LDS counting sort -> exact CSR (compact rows) ----------------
__global__ __launch_bounds__(256) void sortb_k(
    const int* __restrict__ bstart, int2* __restrict__ pairs,
    int* __restrict__ rowptr, const int* __restrict__ Mptr)
{
    __shared__ int2 buf[BCAP];
    __shared__ int2 obuf[BCAP];
    __shared__ int cnt[64];
    __shared__ int cur[64];
    int b = blockIdx.x;
    int s = bstart[b], e = bstart[b + 1];
    int m = e - s;
    int t = threadIdx.x;
    int M = Mptr[0];
    if (t < 64) cnt[t] = 0;
    __syncthreads();
    for (int i = t; i < m; i += 256) {
        int2 p = pairs[s + i];
        buf[i] = p;
        atomicAdd(&cnt[p.x >> 18], 1);
    }
    __syncthreads();
    if (t < 64) {
        int v = cnt[t];
        int incl = v;
        #pragma unroll
        for (int o = 1; o < 64; o <<= 1) {
            int u = __shfl_up(incl, o);
            if (t >= o) incl += u;
        }
        cur[t] = incl - v;
        int n = (b << 6) + t;
        if (n < M) rowptr[n] = s + incl - v;
    }
    __syncthreads();
    for (int i = t; i < m; i += 256) {
        int2 p = buf[i];
        int dst = atomicAdd(&cur[p.x >> 18], 1);
        obuf[dst] = make_int2(p.x & 0x3FFFF, p.y);
    }
    __syncthreads();
    for (int i = t; i < m; i += 256)
        pairs[s + i] = obuf[i];
}

// ---------------- Layer-1 gather: one wave per needed (compact) row ----------------
__global__ __launch_bounds__(256) void gather1_k(
    const int* __restrict__ rowptr, const int2* __restrict__ pairs,
    const float* __restrict__ x, float* __restrict__ side,
    const int* __restrict__ Mptr)
{
    int gtid = blockIdx.x * blockDim.x + threadIdx.x;
    int wave = gtid >> 6;
    int lane = threadIdx.x & 63;
    if (wave >= Mptr[0]) return;
    int s  = rowptr[wave];
    int ep = rowptr[wave + 1];

    float acc = 0.0f;
    for (int base = s; base < ep; base += 64) {
        int2 p = make_int2(0, 0);
        if (base + lane < ep) p = pairs[base + lane];
        int cnt4 = (min(ep - base, 64) + 3) & ~3;
        for (int j = 0; j < cnt4; j += 4) {
            int c0 = __shfl(p.x, j + 0);
            int c1 = __shfl(p.x, j + 1);
            int c2 = __shfl(p.x, j + 2);
            int c3 = __shfl(p.x, j + 3);
            float v0 = __int_as_float(__shfl(p.y, j + 0));
            float v1 = __int_as_float(__shfl(p.y, j + 1));
            float v2 = __int_as_float(__shfl(p.y, j + 2));
            float v3 = __int_as_float(__shfl(p.y, j + 3));
            float f0 = x[(size_t)c0 * D + lane];
            float f1 = x[(size_t)c1 * D + lane];
            float f2 = x[(size_t)c2 * D + lane];
            float f3 = x[(size_t)c3 * D + lane];
            acc = fmaf(v0, f0, acc);
            acc = fmaf(v1, f1, acc);
            acc = fmaf(v2, f2, acc);
            acc = fmaf(v3, f3, acc);
        }
    }
    side[(size_t)wave * D + lane] = acc;
}

// ---------------- Layer-2 gather (sampled): e1 via compact idx ----------------
__global__ __launch_bounds__(256) void gather2_k(
    const int* __restrict__ rowptr, const int2* __restrict__ pairs,
    const float* __restrict__ e1c, const int* __restrict__ idx,
    float* __restrict__ side2c, float* __restrict__ egoc,
    const int* __restrict__ u, const int* __restrict__ it, int batch)
{
    int gtid = blockIdx.x * blockDim.x + threadIdx.x;
    int wave = gtid >> 6;
    int lane = threadIdx.x & 63;
    if (wave >= 2 * batch) return;
    int n = (wave < batch) ? u[wave] : N_USERS_C + it[wave - batch];
    int cr = idx[n];
    int s  = rowptr[cr];
    int ep = rowptr[cr + 1];

    float acc = 0.0f;
    for (int base = s; base < ep; base += 64) {
        int2 p = make_int2(0, 0);
        if (base + lane < ep) p = pairs[base + lane];
        int cnt = min(ep - base, 64);
        for (int j = 0; j < cnt; ++j) {
            int   c = __shfl(p.x, j);
            float v = __int_as_float(__shfl(p.y, j));
            acc = fmaf(v, e1c[(size_t)idx[c] * D + lane], acc);
        }
    }
    side2c[(size_t)wave * D + lane] = acc;
    egoc[(size_t)wave * D + lane] = e1c[(size_t)cr * D + lane];
}

// ---------------- Tiled transform ----------------
// S compact-indexed; E = Eb[list[row]] if list else Eb[row]; out compact-indexed.
__global__ __launch_bounds__(256) void transform_k(
    const float* __restrict__ S, const float* __restrict__ Eb,
    const float* __restrict__ Wg, const float* __restrict__ bg,
    const float* __restrict__ Wb, const float* __restrict__ bb,
    float* __restrict__ out, const int* __restrict__ list,
    const int* __restrict__ Mptr, int nrows)
{
    __shared__ __align__(16) float sWg[D * D];
    __shared__ __align__(16) float sWb[D * D];
    __shared__ __align__(16) float sAT[D][SPAD];
    __shared__ __align__(16) float sBT[D][SPAD];

    int nr = Mptr ? Mptr[0] : nrows;
    int t  = threadIdx.x;
    int tc = t & 15;
    int tr = t >> 4;
    int r0 = blockIdx.x * 64;
    if (r0 >= nr) return;

    for (int i = t; i < D * D; i += 256) {
        sWg[i] = Wg[i];
        sWb[i] = Wb[i];
    }
    for (int itr = 0; itr < 4; ++itr) {
        int rr  = itr * 16 + (t >> 4);
        int row = r0 + rr;
        float4 sv = make_float4(0.f, 0.f, 0.f, 0.f);
        float4 ev = sv;
        if (row < nr) {
            sv = *(const float4*)&S[(size_t)row * D + tc * 4];
            int er = list ? list[row] : row;
            ev = *(const float4*)&Eb[(size_t)er * D + tc * 4];
        }
        sAT[tc * 4 + 0][rr] = sv.x;
        sAT[tc * 4 + 1][rr] = sv.y;
        sAT[tc * 4 + 2][rr] = sv.z;
        sAT[tc * 4 + 3][rr] = sv.w;
        sBT[tc * 4 + 0][rr] = sv.x * ev.x;
        sBT[tc * 4 + 1][rr] = sv.y * ev.y;
        sBT[tc * 4 + 2][rr] = sv.z * ev.z;
        sBT[tc * 4 + 3][rr] = sv.w * ev.w;
    }
    __syncthreads();

    float acc[4][4] = {};
    for (int k = 0; k < D; ++k) {
        float4 a4 = *(const float4*)&sAT[k][tr * 4];
        float4 b4 = *(const float4*)&sBT[k][tr * 4];
        float4 g4 = *(const float4*)&sWg[k * D + tc * 4];
        float4 w4 = *(const float4*)&sWb[k * D + tc * 4];
        float av[4] = {a4.x, a4.y, a4.z, a4.w};
        float bv[4] = {b4.x, b4.y, b4.z, b4.w};
        float gv[4] = {g4.x, g4.y, g4.z, g4.w};
        float wv[4] = {w4.x, w4.y, w4.z, w4.w};
        #pragma unroll
        for (int i = 0; i < 4; ++i)
            #pragma unroll
            for (int j = 0; j < 4; ++j)
                acc[i][j] = fmaf(av[i], gv[j], fmaf(bv[i], wv[j], acc[i][j]));
    }

    float4 bgv = *(const float4*)&bg[tc * 4];
    float4 bbv = *(const float4*)&bb[tc * 4];
    float bias[4] = {bgv.x + bbv.x, bgv.y + bbv.y, bgv.z + bbv.z, bgv.w + bbv.w};

    float vv[4][4];
    float ss[4] = {0.f, 0.f, 0.f, 0.f};
    #pragma unroll
    for (int i = 0; i < 4; ++i) {
        #pragma unroll
        for (int j = 0; j < 4; ++j) {
            float v = acc[i][j] + bias[j];
            v = (v > 0.0f) ? v : 0.2f * v;
            vv[i][j] = v;
            ss[i] += v * v;
        }
    }
    #pragma unroll
    for (int i = 0; i < 4; ++i) {
        #pragma unroll
        for (int off = 1; off < 16; off <<= 1)
            ss[i] += __shfl_xor(ss[i], off);
    }
    #pragma unroll
    for (int i = 0; i < 4; ++i) {
        int row = r0 + tr * 4 + i;
        if (row < nr) {
            float inv = 1.0f / fmaxf(sqrtf(ss[i]), 1e-12f);
            float4 o = make_float4(vv[i][0] * inv, vv[i][1] * inv,
                                   vv[i][2] * inv, vv[i][3] * inv);
            *(float4*)&out[(size_t)row * D + tc * 4] = o;
        }
    }
}

// ---------------- Readout ----------------
__global__ __launch_bounds__(256) void gamma_k(
    const float* __restrict__ x, const float* __restrict__ e1c,
    const int* __restrict__ idx, const float* __restrict__ e2c,
    const int* __restrict__ users, const int* __restrict__ items,
    float* __restrict__ gamma, int batch)
{
    int gtid = blockIdx.x * blockDim.x + threadIdx.x;
    int wave = gtid >> 6;
    int lane = threadIdx.x & 63;
    if (wave >= batch) return;
    size_t uu = (size_t)users[wave];
    size_t tt = (size_t)(N_USERS_C + items[wave]);
    float acc = x[uu * D + lane] * x[tt * D + lane]
              + e1c[(size_t)idx[uu] * D + lane] * e1c[(size_t)idx[tt] * D + lane]
              + e2c[(size_t)wave * D + lane] * e2c[(size_t)(batch + wave) * D + lane];
    #pragma unroll
    for (int off = 1; off < 64; off <<= 1) acc += __shfl_xor(acc, off);
    if (lane == 0) gamma[wave] = acc;
}

extern "C" void kernel_launch(void* const* d_in, const int* in_sizes, int n_in,
                              void* d_out, int out_size, void* d_ws, size_t ws_size,
                              hipStream_t stream) {
    const int*   rows  = (const int*)d_in[0];
    const int*   cols  = (const int*)d_in[1];
    const float* vals  = (const float*)d_in[2];
    const float* x     = (const float*)d_in[3];
    const int*   users = (const int*)d_in[4];
    const int*   items = (const int*)d_in[5];
    const float* Wg0 = (const float*)d_in[6];
    const float* bg0 = (const float*)d_in[7];
    const float* Wb0 = (const float*)d_in[8];
    const float* bb0 = (const float*)d_in[9];
    const float* Wg1 = (const float*)d_in[10];
    const float* bg1 = (const float*)d_in[11];
    const float* Wb1 = (const float*)d_in[12];
    const float* bb1 = (const float*)d_in[13];

    int nnz   = in_sizes[0];
    int batch = in_sizes[4];
    float* out = (float*)d_out;

    size_t emb = (size_t)N_NODES_C * D;
    float* A       = (float*)d_ws;                 // e1c [M x 64], M <= 150k
    float* Sbuf    = A + emb;                      // side_c; aliases pairs1 / layer2 compacts
    int*   bstart  = (int*)(Sbuf + emb);           // NB+1 (+pad)
    int*   sstart  = bstart + (NB + 2);            // NSUP+1 (+pad)
    int*   bcountP = sstart + (NSUP + 2);
    int*   scountP = bcountP + NB * CPAD;          // contiguous with bcountP
    int*   bcur    = scountP + NSUP * CPAD;
    int*   scur    = bcur + NB * CPAD;
    int*   rowptr  = scur + NSUP * CPAD;           // M+1 (alloc N+2)
    int*   idx     = rowptr + N_NODES_C + 2;       // [N]
    int*   list    = idx + N_NODES_C;              // [N]
    int*   bsum    = list + N_NODES_C;             // [1024]
    int*   Mptr    = bsum + 1024;                  // [4]
    unsigned char* need = (unsigned char*)(Mptr + 4);        // [N]
    unsigned char* samp = need + N_NODES_C;                  // [N]
    int2*  pairs   = (int2*)(((size_t)(samp + N_NODES_C) + 15) & ~(size_t)15);

    int2*  pairs1 = (int2*)Sbuf;                   // build-time only
    float* side2c = Sbuf;                          // layer-2 compacts (after transform1)
    float* egoc   = Sbuf + (size_t)2 * 2048 * D;
    float* e2c    = egoc + (size_t)2 * 2048 * D;

    int nscan = (N_NODES_C + 1023) / 1024;         // 147

    // --- needed-set mark + compact ---
    hipMemsetAsync(bcountP, 0, (NB + NSUP) * CPAD * sizeof(int), stream);
    hipMemsetAsync(need, 0, 2 * N_NODES_C, stream);
    mark1_k<<<(2 * batch + 255) / 256, 256, 0, stream>>>(users, items, samp, need, batch);
    mark2_k<<<1024, 256, 0, stream>>>(rows, cols, samp, need, nnz);
    scan1_k<<<nscan, 1024, 0, stream>>>(need, idx, bsum, N_NODES_C);
    scan2_k<<<1, 1024, 0, stream>>>(bsum, nscan, Mptr);
    scan3_k<<<(N_NODES_C + 255) / 256, 256, 0, stream>>>(bsum, idx, need, list, N_NODES_C);

    // --- two-level bucket build over needed edges (compact row space) ---
    histc_k<<<256, 256, 0, stream>>>(rows, idx, bcountP, scountP, nnz);
    scanb_k<<<1, 1024, 0, stream>>>(bcountP, bstart, NB);
    scanb_k<<<1, 1024, 0, stream>>>(scountP, sstart, NSUP);
    initcur2_k<<<(NB + 255) / 256, 256, 0, stream>>>(bstart, bcur, sstart, scur, rowptr, Mptr);
    int g1 = (nnz + 4687) / 4688;
    s1_k<<<g1, 256, 0, stream>>>(rows, cols, vals, idx, scur, pairs1, nnz);
    s2_k<<<NSUP * BPS, 256, 0, stream>>>(sstart, pairs1, bcur, pairs);
    sortb_k<<<NB, 256, 0, stream>>>(bstart, pairs, rowptr, Mptr);

    // --- Layer 1 over M needed rows (worst-case grid, early exit on M) ---
    gather1_k<<<(N_NODES_C * 64 + 255) / 256, 256, 0, stream>>>(
        rowptr, pairs, x, Sbuf, Mptr);
    transform_k<<<(N_NODES_C + 63) / 64, 256, 0, stream>>>(
        Sbuf, x, Wg0, bg0, Wb0, bb0, A, list, Mptr, 0);

    // --- Layer 2 (sampled 2*batch rows) ---
    gather2_k<<<(2 * batch * 64 + 255) / 256, 256, 0, stream>>>(
        rowptr, pairs, A, idx, side2c, egoc, users, items, batch);
    transform_k<<<(2 * batch + 63) / 64, 256, 0, stream>>>(
        side2c, egoc, Wg1, bg1, Wb1, bb1, e2c, nullptr, nullptr, 2 * batch);

    // --- Readout ---
    gamma_k<<<(batch * 64 + 255) / 256, 256, 0, stream>>>(
        x, A, idx, e2c, users, items, out, batch);
}